// Round 1
// baseline (661.386 us; speedup 1.0000x reference)
//
#include <hip/hip_runtime.h>
#include <hip/hip_bf16.h>
#include <math.h>

// Problem constants (from reference)
#define S_LEN  2048
#define HID    1024
#define NHEADS 16
#define NE     256
#define NMEN   1024
#define NP     2048
#define PHID   1024

// ---------------------------------------------------------------------------
// Helpers
// ---------------------------------------------------------------------------
__device__ inline void seg_bounds(const int* __restrict__ entity_ids, int e,
                                  int& start, int& end) {
    // entity_ids sorted ascending, length NMEN
    int lo = 0, hi = NMEN;
    while (lo < hi) { int mid = (lo + hi) >> 1; if (entity_ids[mid] < e) lo = mid + 1; else hi = mid; }
    start = lo;
    hi = NMEN;
    while (lo < hi) { int mid = (lo + hi) >> 1; if (entity_ids[mid] <= e) lo = mid + 1; else hi = mid; }
    end = lo;
}

// ---------------------------------------------------------------------------
// 1) Entity embedding: segment logsumexp over gathered sequence rows
//    grid = NE blocks, 256 threads
// ---------------------------------------------------------------------------
__global__ void ent_emb_kernel(const float* __restrict__ seq,        // [S,H]
                               const int* __restrict__ mention_idx,  // [NM]
                               const int* __restrict__ entity_ids,   // [NM]
                               float* __restrict__ ent_emb)          // [E,H]
{
    __shared__ int sb[2];
    int e = blockIdx.x;
    if (threadIdx.x == 0) { int s, t; seg_bounds(entity_ids, e, s, t); sb[0] = s; sb[1] = t; }
    __syncthreads();
    int start = sb[0], end = sb[1];
    int cnt = end - start;
    for (int col = threadIdx.x; col < HID; col += blockDim.x) {
        if (cnt <= 0) { ent_emb[(long)e * HID + col] = 0.f; continue; }
        float m = -INFINITY;
        for (int i = start; i < end; ++i) {
            int row = mention_idx[i];
            m = fmaxf(m, seq[(long)row * HID + col]);
        }
        float ssum = 0.f;
        for (int i = start; i < end; ++i) {
            int row = mention_idx[i];
            ssum += expf(seq[(long)row * HID + col] - m);
        }
        ent_emb[(long)e * HID + col] = m + logf(ssum);
    }
}

// ---------------------------------------------------------------------------
// 2) Entity attention: segment mean of gathered attention rows
//    grid = (NE, NHEADS), 256 threads
// ---------------------------------------------------------------------------
__global__ void ent_att_kernel(const float* __restrict__ att,        // [HEADS,S,S]
                               const int* __restrict__ mention_idx,
                               const int* __restrict__ entity_ids,
                               float* __restrict__ ent_att)          // [E,HEADS,S]
{
    __shared__ int sb[2];
    int e = blockIdx.x, h = blockIdx.y;
    if (threadIdx.x == 0) { int s, t; seg_bounds(entity_ids, e, s, t); sb[0] = s; sb[1] = t; }
    __syncthreads();
    int start = sb[0], end = sb[1];
    int cnt = end - start;
    float inv = 1.f / fmaxf((float)cnt, 1.f);
    for (int s = threadIdx.x; s < S_LEN; s += blockDim.x) {
        float acc = 0.f;
        for (int i = start; i < end; ++i) {
            int row = mention_idx[i];
            acc += att[((long)h * S_LEN + row) * S_LEN + s];
        }
        ent_att[((long)e * NHEADS + h) * S_LEN + s] = acc * inv;
    }
}

// ---------------------------------------------------------------------------
// 3) Pair attention: head-contracted product + normalize
//    grid = NP blocks, 256 threads
// ---------------------------------------------------------------------------
__global__ void pair_att_kernel(const float* __restrict__ ent_att,   // [E,HEADS,S]
                                const int* __restrict__ pair_h,
                                const int* __restrict__ pair_t,
                                float* __restrict__ pair_att)        // [P,S]
{
    __shared__ float row[S_LEN];
    __shared__ float wsum[4];
    int p = blockIdx.x;
    const float* ha = ent_att + (long)pair_h[p] * NHEADS * S_LEN;
    const float* ta = ent_att + (long)pair_t[p] * NHEADS * S_LEN;
    float psum = 0.f;
    for (int s = threadIdx.x; s < S_LEN; s += blockDim.x) {
        float acc = 0.f;
#pragma unroll
        for (int h = 0; h < NHEADS; ++h)
            acc += ha[h * S_LEN + s] * ta[h * S_LEN + s];
        row[s] = acc;
        psum += acc;
    }
    // block reduce psum (256 threads = 4 waves of 64)
#pragma unroll
    for (int off = 32; off > 0; off >>= 1)
        psum += __shfl_down(psum, off, 64);
    int lane = threadIdx.x & 63, wid = threadIdx.x >> 6;
    if (lane == 0) wsum[wid] = psum;
    __syncthreads();
    float total = wsum[0] + wsum[1] + wsum[2] + wsum[3];
    float inv = 1.f / (total + 1e-6f);
    for (int s = threadIdx.x; s < S_LEN; s += blockDim.x)
        pair_att[(long)p * S_LEN + s] = row[s] * inv;
}

// ---------------------------------------------------------------------------
// 4) Generic fp32 GEMM: C[M,N] = A[M,K] @ B[K,N]
//    64x64 tile, BK=16, 256 threads, 4x4 per-thread microtile.
//    Requires M%64==0, N%64==0, K%16==0 (true for all call sites).
// ---------------------------------------------------------------------------
#define BM 64
#define BN 64
#define BK 16
__launch_bounds__(256)
__global__ void gemm_f32(const float* __restrict__ A, const float* __restrict__ B,
                         float* __restrict__ C, int M, int N, int K)
{
    __shared__ float As[BK][BM + 1];
    __shared__ float Bs[BK][BN];
    int bm = blockIdx.y * BM;
    int bn = blockIdx.x * BN;
    int tid = threadIdx.x;
    int tm = tid >> 4;    // 0..15
    int tn = tid & 15;    // 0..15
    float acc[4][4] = {{0.f}};
    for (int k0 = 0; k0 < K; k0 += BK) {
        // A tile 64x16 (row r, col c), stored transposed As[c][r]
#pragma unroll
        for (int i = 0; i < 4; ++i) {
            int idx = tid + i * 256;
            int r = idx >> 4;
            int c = idx & 15;
            As[c][r] = A[(long)(bm + r) * K + k0 + c];
        }
        // B tile 16x64
#pragma unroll
        for (int i = 0; i < 4; ++i) {
            int idx = tid + i * 256;
            int r = idx >> 6;
            int c = idx & 63;
            Bs[r][c] = B[(long)(k0 + r) * N + bn + c];
        }
        __syncthreads();
#pragma unroll
        for (int k = 0; k < BK; ++k) {
            float a[4], b[4];
#pragma unroll
            for (int i = 0; i < 4; ++i) a[i] = As[k][tm * 4 + i];
#pragma unroll
            for (int j = 0; j < 4; ++j) b[j] = Bs[k][tn * 4 + j];
#pragma unroll
            for (int i = 0; i < 4; ++i)
#pragma unroll
                for (int j = 0; j < 4; ++j)
                    acc[i][j] += a[i] * b[j];
        }
        __syncthreads();
    }
#pragma unroll
    for (int i = 0; i < 4; ++i)
#pragma unroll
        for (int j = 0; j < 4; ++j)
            C[(long)(bm + tm * 4 + i) * N + bn + tn * 4 + j] = acc[i][j];
}

// ---------------------------------------------------------------------------
// 5) zs/zo elementwise: tanh(gathered entity proj + bias + ctx_p)
//    grid over P*PH
// ---------------------------------------------------------------------------
__global__ void zs_zo_kernel(const float* __restrict__ ctxp,   // [P,PH]
                             const float* __restrict__ eh,     // [E,PH]
                             const float* __restrict__ et,     // [E,PH]
                             const float* __restrict__ b_head, // [PH]
                             const float* __restrict__ b_tail, // [PH]
                             const int* __restrict__ pair_h,
                             const int* __restrict__ pair_t,
                             float* __restrict__ zs, float* __restrict__ zo)
{
    long idx = (long)blockIdx.x * blockDim.x + threadIdx.x;
    if (idx >= (long)NP * PHID) return;
    int p = (int)(idx >> 10);      // / PHID
    int j = (int)(idx & (PHID - 1));
    float c = ctxp[idx];
    zs[idx] = tanhf(eh[(long)pair_h[p] * PHID + j] + b_head[j] + c);
    zo[idx] = tanhf(et[(long)pair_t[p] * PHID + j] + b_tail[j] + c);
}

// ---------------------------------------------------------------------------
// 6) Final dot: logits[p] = sum_j t[p,j]*zo[p,j] + b_bil
//    grid = NP blocks, 256 threads
// ---------------------------------------------------------------------------
__global__ void logits_kernel(const float* __restrict__ t,
                              const float* __restrict__ zo,
                              const float* __restrict__ b_bil,
                              float* __restrict__ out)
{
    __shared__ float wsum[4];
    int p = blockIdx.x;
    float acc = 0.f;
    for (int j = threadIdx.x; j < PHID; j += blockDim.x)
        acc += t[(long)p * PHID + j] * zo[(long)p * PHID + j];
#pragma unroll
    for (int off = 32; off > 0; off >>= 1)
        acc += __shfl_down(acc, off, 64);
    int lane = threadIdx.x & 63, wid = threadIdx.x >> 6;
    if (lane == 0) wsum[wid] = acc;
    __syncthreads();
    if (threadIdx.x == 0)
        out[p] = wsum[0] + wsum[1] + wsum[2] + wsum[3] + b_bil[0];
}

// ---------------------------------------------------------------------------
// Launch
// ---------------------------------------------------------------------------
extern "C" void kernel_launch(void* const* d_in, const int* in_sizes, int n_in,
                              void* d_out, int out_size, void* d_ws, size_t ws_size,
                              hipStream_t stream)
{
    const float* seq        = (const float*)d_in[0];   // [S,H]
    const float* attention  = (const float*)d_in[1];   // [HEADS,S,S]
    const int*   mention_idx= (const int*)  d_in[2];   // [NM]
    const int*   entity_ids = (const int*)  d_in[3];   // [NM]
    const int*   pair_h     = (const int*)  d_in[4];   // [P]
    const int*   pair_t     = (const int*)  d_in[5];   // [P]
    const float* W_head     = (const float*)d_in[6];   // [H,PH]
    const float* b_head     = (const float*)d_in[7];   // [PH]
    const float* W_tail     = (const float*)d_in[8];   // [H,PH]
    const float* b_tail     = (const float*)d_in[9];   // [PH]
    const float* W_ctx      = (const float*)d_in[10];  // [H,PH]
    const float* W_bil      = (const float*)d_in[11];  // [PH,PH]
    const float* b_bil      = (const float*)d_in[12];  // scalar
    float* out = (float*)d_out;                        // [P]

    // Workspace layout (floats). Total = 23,855,104 floats = ~95.4 MB.
    float* ws       = (float*)d_ws;
    float* ent_emb  = ws;                         // E*H      = 262144
    float* eh       = ent_emb  + (long)NE * HID;  // E*PH     = 262144
    float* et       = eh       + (long)NE * PHID; // E*PH     = 262144
    float* ent_att  = et       + (long)NE * PHID; // E*HEADS*S= 8388608
    float* pair_att = ent_att  + (long)NE * NHEADS * S_LEN;  // P*S = 4194304
    float* contexts = pair_att + (long)NP * S_LEN;           // P*H = 2097152
    float* ctxp     = contexts + (long)NP * HID;             // P*PH
    float* zs       = ctxp     + (long)NP * PHID;
    float* zo       = zs       + (long)NP * PHID;
    float* tbuf     = zo       + (long)NP * PHID;

    // 1) entity embeddings (segment logsumexp)
    ent_emb_kernel<<<NE, 256, 0, stream>>>(seq, mention_idx, entity_ids, ent_emb);

    // 2) entity attention (segment mean)
    ent_att_kernel<<<dim3(NE, NHEADS), 256, 0, stream>>>(attention, mention_idx, entity_ids, ent_att);

    // 3) pair attention (head contraction + normalize)
    pair_att_kernel<<<NP, 256, 0, stream>>>(ent_att, pair_h, pair_t, pair_att);

    // 4) contexts = pair_att @ seq   [P,S]@[S,H]
    gemm_f32<<<dim3(HID / BN, NP / BM), 256, 0, stream>>>(pair_att, seq, contexts, NP, HID, S_LEN);

    // 5) ctxp = contexts @ W_ctx     [P,H]@[H,PH]
    gemm_f32<<<dim3(PHID / BN, NP / BM), 256, 0, stream>>>(contexts, W_ctx, ctxp, NP, PHID, HID);

    // 6) eh = ent_emb @ W_head ; et = ent_emb @ W_tail   [E,H]@[H,PH]
    gemm_f32<<<dim3(PHID / BN, NE / BM), 256, 0, stream>>>(ent_emb, W_head, eh, NE, PHID, HID);
    gemm_f32<<<dim3(PHID / BN, NE / BM), 256, 0, stream>>>(ent_emb, W_tail, et, NE, PHID, HID);

    // 7) zs = tanh(eh[pair_h] + b_head + ctxp); zo = tanh(et[pair_t] + b_tail + ctxp)
    {
        long total = (long)NP * PHID;
        int blocks = (int)((total + 255) / 256);
        zs_zo_kernel<<<blocks, 256, 0, stream>>>(ctxp, eh, et, b_head, b_tail, pair_h, pair_t, zs, zo);
    }

    // 8) tbuf = zs @ W_bil   [P,PH]@[PH,PH]
    gemm_f32<<<dim3(PHID / BN, NP / BM), 256, 0, stream>>>(zs, W_bil, tbuf, NP, PHID, PHID);

    // 9) logits[p] = dot(tbuf[p], zo[p]) + b_bil
    logits_kernel<<<NP, 256, 0, stream>>>(tbuf, zo, b_bil, out);
}

// Round 2
// 293.948 us; speedup vs baseline: 2.2500x; 2.2500x over previous
//
#include <hip/hip_runtime.h>
#include <hip/hip_bf16.h>
#include <math.h>
#include <stdint.h>

// Problem constants
#define S_LEN  2048
#define HID    1024
#define NHEADS 16
#define NE     256
#define NMEN   1024
#define NP     2048
#define PHID   1024

typedef __attribute__((ext_vector_type(8))) short bf16x8;   // 8 bf16 (4 VGPRs)
typedef __attribute__((ext_vector_type(4))) float f32x4;    // MFMA accumulator

// ---------------------------------------------------------------------------
// Helpers
// ---------------------------------------------------------------------------
__device__ inline void seg_bounds(const int* __restrict__ entity_ids, int e,
                                  int& start, int& end) {
    int lo = 0, hi = NMEN;
    while (lo < hi) { int mid = (lo + hi) >> 1; if (entity_ids[mid] < e) lo = mid + 1; else hi = mid; }
    start = lo;
    hi = NMEN;
    while (lo < hi) { int mid = (lo + hi) >> 1; if (entity_ids[mid] <= e) lo = mid + 1; else hi = mid; }
    end = lo;
}

__device__ __forceinline__ void load_lds16(const void* g, void* l) {
    __builtin_amdgcn_global_load_lds(
        (const __attribute__((address_space(1))) uint32_t*)g,
        (__attribute__((address_space(3))) uint32_t*)l,
        16, 0, 0);
}

// ---------------------------------------------------------------------------
// Transpose + fp32->bf16: out[c][r] = bf16(in[r][c]).  R,C multiples of 32.
// grid (C/32, R/32), 256 threads
// ---------------------------------------------------------------------------
__global__ void transpose_bf16(const float* __restrict__ in, __hip_bfloat16* __restrict__ out,
                               int R, int C)
{
    __shared__ float t[32][33];
    int r0 = blockIdx.y * 32, c0 = blockIdx.x * 32;
    int j = threadIdx.x & 31, i0 = threadIdx.x >> 5;   // 8 rows per pass
    for (int i = i0; i < 32; i += 8)
        t[i][j] = in[(long)(r0 + i) * C + c0 + j];
    __syncthreads();
    for (int i = i0; i < 32; i += 8)
        out[(long)(c0 + i) * R + r0 + j] = __float2bfloat16(t[j][i]);
}

// ---------------------------------------------------------------------------
// 1) Entity embedding: segment logsumexp -> bf16 [E][H]
//    grid NE, 256 threads (H/4 = 256 float4 columns, one per thread)
// ---------------------------------------------------------------------------
__global__ void ent_emb_kernel(const float4* __restrict__ seq4,     // [S][H/4]
                               const int* __restrict__ mention_idx,
                               const int* __restrict__ entity_ids,
                               __hip_bfloat16* __restrict__ ent_emb) // [E][H] bf16
{
    __shared__ int sb[2];
    int e = blockIdx.x;
    if (threadIdx.x == 0) { int s, t; seg_bounds(entity_ids, e, s, t); sb[0] = s; sb[1] = t; }
    __syncthreads();
    int start = sb[0], end = sb[1];
    int col4 = threadIdx.x;          // 0..255
    union { __hip_bfloat16 h[4]; uint2 u2; } pk;
    if (end <= start) {
        pk.h[0] = pk.h[1] = pk.h[2] = pk.h[3] = __float2bfloat16(0.f);
        ((uint2*)ent_emb)[(long)e * 256 + col4] = pk.u2;
        return;
    }
    float mx = -INFINITY, my = -INFINITY, mz = -INFINITY, mw = -INFINITY;
    for (int i = start; i < end; ++i) {
        float4 v = seq4[(long)mention_idx[i] * 256 + col4];
        mx = fmaxf(mx, v.x); my = fmaxf(my, v.y); mz = fmaxf(mz, v.z); mw = fmaxf(mw, v.w);
    }
    float sx = 0.f, sy = 0.f, sz = 0.f, sw = 0.f;
    for (int i = start; i < end; ++i) {
        float4 v = seq4[(long)mention_idx[i] * 256 + col4];
        sx += expf(v.x - mx); sy += expf(v.y - my); sz += expf(v.z - mz); sw += expf(v.w - mw);
    }
    pk.h[0] = __float2bfloat16(mx + logf(sx));
    pk.h[1] = __float2bfloat16(my + logf(sy));
    pk.h[2] = __float2bfloat16(mz + logf(sz));
    pk.h[3] = __float2bfloat16(mw + logf(sw));
    ((uint2*)ent_emb)[(long)e * 256 + col4] = pk.u2;
}

// ---------------------------------------------------------------------------
// 2) Entity attention: segment mean (fp32), float4 vectorized
//    grid (NE, NHEADS), 256 threads
// ---------------------------------------------------------------------------
__global__ void ent_att_kernel(const float4* __restrict__ att4,     // [HEADS][S][S/4]
                               const int* __restrict__ mention_idx,
                               const int* __restrict__ entity_ids,
                               float4* __restrict__ out4)           // [E][HEADS][S/4]
{
    __shared__ int sb[2];
    int e = blockIdx.x, h = blockIdx.y;
    if (threadIdx.x == 0) { int s, t; seg_bounds(entity_ids, e, s, t); sb[0] = s; sb[1] = t; }
    __syncthreads();
    int start = sb[0], end = sb[1];
    float inv = 1.f / fmaxf((float)(end - start), 1.f);
    for (int s4 = threadIdx.x; s4 < S_LEN / 4; s4 += 256) {
        float ax = 0.f, ay = 0.f, az = 0.f, aw = 0.f;
        for (int i = start; i < end; ++i) {
            float4 v = att4[((long)h * S_LEN + mention_idx[i]) * (S_LEN / 4) + s4];
            ax += v.x; ay += v.y; az += v.z; aw += v.w;
        }
        out4[((long)e * NHEADS + h) * (S_LEN / 4) + s4] = make_float4(ax * inv, ay * inv, az * inv, aw * inv);
    }
}

// ---------------------------------------------------------------------------
// 3) Pair attention -> normalized bf16 [P][S]
//    grid NP, 256 threads
// ---------------------------------------------------------------------------
__global__ void pair_att_kernel(const float4* __restrict__ ent_att4, // [E][HEADS][S/4]
                                const int* __restrict__ pair_h,
                                const int* __restrict__ pair_t,
                                __hip_bfloat16* __restrict__ pair_att) // [P][S] bf16
{
    __shared__ float4 row[S_LEN / 4];
    __shared__ float wsum[4];
    int p = blockIdx.x;
    const float4* ha = ent_att4 + (long)pair_h[p] * NHEADS * (S_LEN / 4);
    const float4* ta = ent_att4 + (long)pair_t[p] * NHEADS * (S_LEN / 4);
    float psum = 0.f;
    for (int s4 = threadIdx.x; s4 < S_LEN / 4; s4 += 256) {
        float ax = 0.f, ay = 0.f, az = 0.f, aw = 0.f;
#pragma unroll
        for (int h = 0; h < NHEADS; ++h) {
            float4 x = ha[h * (S_LEN / 4) + s4];
            float4 y = ta[h * (S_LEN / 4) + s4];
            ax += x.x * y.x; ay += x.y * y.y; az += x.z * y.z; aw += x.w * y.w;
        }
        row[s4] = make_float4(ax, ay, az, aw);
        psum += ax + ay + az + aw;
    }
#pragma unroll
    for (int off = 32; off > 0; off >>= 1)
        psum += __shfl_down(psum, off, 64);
    int lane = threadIdx.x & 63, wid = threadIdx.x >> 6;
    if (lane == 0) wsum[wid] = psum;
    __syncthreads();
    float inv = 1.f / (wsum[0] + wsum[1] + wsum[2] + wsum[3] + 1e-6f);
    for (int s4 = threadIdx.x; s4 < S_LEN / 4; s4 += 256) {
        float4 v = row[s4];
        union { __hip_bfloat16 h[4]; uint2 u2; } pk;
        pk.h[0] = __float2bfloat16(v.x * inv);
        pk.h[1] = __float2bfloat16(v.y * inv);
        pk.h[2] = __float2bfloat16(v.z * inv);
        pk.h[3] = __float2bfloat16(v.w * inv);
        ((uint2*)pair_att)[(long)p * (S_LEN / 4) + s4] = pk.u2;
    }
}

// ---------------------------------------------------------------------------
// 4) bf16 MFMA GEMM: C[M][N] (+z slice) = A[M][Kstride] @ Bt[N][Kstride]^T
//    over k in [z*kLen, (z+1)*kLen). 128x128 tile, BK=32, 256 threads (4 waves 2x2).
//    M,N multiples of 128; kLen multiple of 32.
// ---------------------------------------------------------------------------
template <int WRITE_BF16>
__launch_bounds__(256)
__global__ void gemm_bt(const __hip_bfloat16* __restrict__ A,
                        const __hip_bfloat16* __restrict__ Bt,
                        void* __restrict__ Cout,
                        int M, int N, int Kstride, int kLen)
{
    __shared__ short As[4][128][8];   // [kg][row][8 bf16]  (8 KB)
    __shared__ short Bs[4][128][8];   // [kg][col][8 bf16]  (8 KB)

    int tid = threadIdx.x;
    int lane = tid & 63, wid = tid >> 6;
    int wr = wid >> 1, wc = wid & 1;          // 2x2 waves, each 64x64 output
    int bm = blockIdx.y * 128, bn = blockIdx.x * 128;
    int kBeg = blockIdx.z * kLen;

    // Per-wave staging assignment: 16 chunks of 1KB (8 A + 8 B), 4 per wave.
    const __hip_bfloat16* gsrc[4];
    void* ldst[4];
#pragma unroll
    for (int i = 0; i < 4; ++i) {
        int c = wid * 4 + i;
        int isA = (c < 8) ? 1 : 0;
        int cc = isA ? c : c - 8;
        int kg = cc >> 1, rh = cc & 1;
        gsrc[i] = (isA ? A + (long)(bm + rh * 64 + lane) * Kstride
                       : Bt + (long)(bn + rh * 64 + lane) * Kstride) + kBeg + kg * 8;
        ldst[i] = isA ? (void*)&As[kg][rh * 64][0] : (void*)&Bs[kg][rh * 64][0];
    }

    f32x4 acc[4][4] = {};
    int kg = lane >> 4, lr = lane & 15;

    for (int k0 = 0; k0 < kLen; k0 += 32) {
#pragma unroll
        for (int i = 0; i < 4; ++i)
            load_lds16(gsrc[i] + k0, ldst[i]);
        __syncthreads();   // drains vmcnt before any wave reads LDS

        bf16x8 af[4], bfr[4];
#pragma unroll
        for (int f = 0; f < 4; ++f) {
            af[f]  = *(const bf16x8*)&As[kg][wr * 64 + f * 16 + lr][0];
            bfr[f] = *(const bf16x8*)&Bs[kg][wc * 64 + f * 16 + lr][0];
        }
#pragma unroll
        for (int fm = 0; fm < 4; ++fm)
#pragma unroll
            for (int fn = 0; fn < 4; ++fn)
                acc[fm][fn] = __builtin_amdgcn_mfma_f32_16x16x32_bf16(af[fm], bfr[fn], acc[fm][fn], 0, 0, 0);
        __syncthreads();   // before overwriting LDS next iter
    }

    // Epilogue: C/D layout col = lane&15, row = (lane>>4)*4 + reg
    int q4 = (lane >> 4) * 4;
#pragma unroll
    for (int fm = 0; fm < 4; ++fm) {
#pragma unroll
        for (int fn = 0; fn < 4; ++fn) {
            int row = bm + wr * 64 + fm * 16 + q4;
            int col = bn + wc * 64 + fn * 16 + lr;
#pragma unroll
            for (int r = 0; r < 4; ++r) {
                long idx = ((long)blockIdx.z * M + row + r) * N + col;
                if (WRITE_BF16)
                    ((__hip_bfloat16*)Cout)[idx] = __float2bfloat16(acc[fm][fn][r]);
                else
                    ((float*)Cout)[idx] = acc[fm][fn][r];
            }
        }
    }
}

// ---------------------------------------------------------------------------
// 5) reduce 4 split-K slices: out[i] = sum_s part[s*n + i]
// ---------------------------------------------------------------------------
__global__ void reduce4_kernel(const float* __restrict__ part, float* __restrict__ out, long n)
{
    long i = (long)blockIdx.x * 256 + threadIdx.x;
    out[i] = part[i] + part[n + i] + part[2 * n + i] + part[3 * n + i];
}

// ---------------------------------------------------------------------------
// 6) zs/zo: zs = tanh(eh[ph]+b_head+ctxp) (bf16), zo = tanh(et[pt]+b_tail+ctxp) (f32)
// ---------------------------------------------------------------------------
__global__ void zs_zo_kernel(const float* __restrict__ ctxp,   // [P][PH]
                             const float* __restrict__ ehet,   // [E][2*PH]
                             const float* __restrict__ b_head,
                             const float* __restrict__ b_tail,
                             const int* __restrict__ pair_h,
                             const int* __restrict__ pair_t,
                             __hip_bfloat16* __restrict__ zs, float* __restrict__ zo)
{
    long idx = (long)blockIdx.x * 256 + threadIdx.x;   // exact: P*PH
    int p = (int)(idx >> 10);
    int j = (int)(idx & (PHID - 1));
    float c = ctxp[idx];
    float a = tanhf(ehet[(long)pair_h[p] * 2048 + j] + b_head[j] + c);
    float b = tanhf(ehet[(long)pair_t[p] * 2048 + 1024 + j] + b_tail[j] + c);
    zs[idx] = __float2bfloat16(a);
    zo[idx] = b;
}

// ---------------------------------------------------------------------------
// 7) logits[p] = dot(tbuf[p], zo[p]) + b_bil   (float4, 1 block per pair)
// ---------------------------------------------------------------------------
__global__ void logits_kernel(const float4* __restrict__ t4,
                              const float4* __restrict__ zo4,
                              const float* __restrict__ b_bil,
                              float* __restrict__ out)
{
    __shared__ float wsum[4];
    int p = blockIdx.x;
    float4 a = t4[(long)p * 256 + threadIdx.x];
    float4 b = zo4[(long)p * 256 + threadIdx.x];
    float acc = a.x * b.x + a.y * b.y + a.z * b.z + a.w * b.w;
#pragma unroll
    for (int off = 32; off > 0; off >>= 1)
        acc += __shfl_down(acc, off, 64);
    int lane = threadIdx.x & 63, wid = threadIdx.x >> 6;
    if (lane == 0) wsum[wid] = acc;
    __syncthreads();
    if (threadIdx.x == 0)
        out[p] = wsum[0] + wsum[1] + wsum[2] + wsum[3] + b_bil[0];
}

// ---------------------------------------------------------------------------
// Launch
// ---------------------------------------------------------------------------
extern "C" void kernel_launch(void* const* d_in, const int* in_sizes, int n_in,
                              void* d_out, int out_size, void* d_ws, size_t ws_size,
                              hipStream_t stream)
{
    const float* seq        = (const float*)d_in[0];
    const float* attention  = (const float*)d_in[1];
    const int*   mention_idx= (const int*)  d_in[2];
    const int*   entity_ids = (const int*)  d_in[3];
    const int*   pair_h     = (const int*)  d_in[4];
    const int*   pair_t     = (const int*)  d_in[5];
    const float* W_head     = (const float*)d_in[6];
    const float* b_head     = (const float*)d_in[7];
    const float* W_tail     = (const float*)d_in[8];
    const float* b_tail     = (const float*)d_in[9];
    const float* W_ctx      = (const float*)d_in[10];
    const float* W_bil      = (const float*)d_in[11];
    const float* b_bil      = (const float*)d_in[12];
    float* out = (float*)d_out;

    // ---- workspace layout (bytes) ----
    char* w = (char*)d_ws;
    __hip_bfloat16* seqT  = (__hip_bfloat16*)w;  w += (long)HID * S_LEN * 2;        // [H][S]   4 MB
    __hip_bfloat16* WctxT = (__hip_bfloat16*)w;  w += (long)PHID * HID * 2;         // [PH][H]  2 MB
    __hip_bfloat16* WhtT  = (__hip_bfloat16*)w;  w += (long)2 * PHID * HID * 2;     // [2PH][H] 4 MB
    __hip_bfloat16* WbilT = (__hip_bfloat16*)w;  w += (long)PHID * PHID * 2;        // [PH][PH] 2 MB
    __hip_bfloat16* embB  = (__hip_bfloat16*)w;  w += (long)NE * HID * 2;           // 0.5 MB
    __hip_bfloat16* pattB = (__hip_bfloat16*)w;  w += (long)NP * S_LEN * 2;         // 8 MB
    __hip_bfloat16* ctxB  = (__hip_bfloat16*)w;  w += (long)NP * HID * 2;           // 4 MB
    __hip_bfloat16* zsB   = (__hip_bfloat16*)w;  w += (long)NP * PHID * 2;          // 4 MB
    float* zo    = (float*)w;                    w += (long)NP * PHID * 4;          // 8 MB
    float* entAtt = (float*)w;                   // 32 MB region; reused below
    // overlays on entAtt region (dead after pair_att):
    float* ctxp  = (float*)((char*)entAtt);                     // 8 MB
    float* ehetP = (float*)((char*)entAtt + 8388608);           // 8 MB (4 split slices)
    float* ehet  = (float*)((char*)entAtt + 16777216);          // 2 MB
    float* tbuf  = (float*)((char*)entAtt + 18874368);          // 8 MB

    // ---- 0) transposes / bf16 conversions ----
    transpose_bf16<<<dim3(HID / 32, S_LEN / 32), 256, 0, stream>>>(seq, seqT, S_LEN, HID);
    transpose_bf16<<<dim3(PHID / 32, HID / 32), 256, 0, stream>>>(W_ctx, WctxT, HID, PHID);
    transpose_bf16<<<dim3(PHID / 32, HID / 32), 256, 0, stream>>>(W_head, WhtT, HID, PHID);
    transpose_bf16<<<dim3(PHID / 32, HID / 32), 256, 0, stream>>>(W_tail, WhtT + (long)PHID * HID, HID, PHID);
    transpose_bf16<<<dim3(PHID / 32, PHID / 32), 256, 0, stream>>>(W_bil, WbilT, PHID, PHID);

    // ---- 1) entity embeddings (bf16) ----
    ent_emb_kernel<<<NE, 256, 0, stream>>>((const float4*)seq, mention_idx, entity_ids, embB);

    // ---- 2) entity attention (fp32) ----
    ent_att_kernel<<<dim3(NE, NHEADS), 256, 0, stream>>>((const float4*)attention, mention_idx, entity_ids,
                                                         (float4*)entAtt);

    // ---- 3) pair attention (bf16, normalized) ----
    pair_att_kernel<<<NP, 256, 0, stream>>>((const float4*)entAtt, pair_h, pair_t, pattB);

    // ---- 4) contexts(bf16) = pair_att @ seq : M=2048,N=1024,K=2048 ----
    gemm_bt<1><<<dim3(HID / 128, NP / 128, 1), 256, 0, stream>>>(pattB, seqT, ctxB, NP, HID, S_LEN, S_LEN);

    // ---- 5) ctxp(f32) = contexts @ W_ctx : M=2048,N=1024,K=1024 ----
    gemm_bt<0><<<dim3(PHID / 128, NP / 128, 1), 256, 0, stream>>>(ctxB, WctxT, ctxp, NP, PHID, HID, HID);

    // ---- 6) ehet partials = ent_emb @ [W_head|W_tail] : M=256,N=2048,K=1024, splitK=4 ----
    gemm_bt<0><<<dim3(2 * PHID / 128, NE / 128, 4), 256, 0, stream>>>(embB, WhtT, ehetP, NE, 2 * PHID, HID, HID / 4);
    reduce4_kernel<<<(int)(((long)NE * 2 * PHID) / 256), 256, 0, stream>>>(ehetP, ehet, (long)NE * 2 * PHID);

    // ---- 7) zs (bf16), zo (f32) ----
    zs_zo_kernel<<<(int)(((long)NP * PHID) / 256), 256, 0, stream>>>(ctxp, ehet, b_head, b_tail,
                                                                    pair_h, pair_t, zsB, zo);

    // ---- 8) tbuf(f32) = zs @ W_bil : M=2048,N=1024,K=1024 ----
    gemm_bt<0><<<dim3(PHID / 128, NP / 128, 1), 256, 0, stream>>>(zsB, WbilT, tbuf, NP, PHID, HID, HID);

    // ---- 9) logits ----
    logits_kernel<<<NP, 256, 0, stream>>>((const float4*)tbuf, (const float4*)zo, b_bil, out);
}

// Round 3
// 198.298 us; speedup vs baseline: 3.3353x; 1.4824x over previous
//
#include <hip/hip_runtime.h>
#include <hip/hip_bf16.h>
#include <math.h>
#include <stdint.h>

// Problem constants
#define S_LEN  2048
#define HID    1024
#define NHEADS 16
#define NE     256
#define NMEN   1024
#define NP     2048
#define PHID   1024

typedef __attribute__((ext_vector_type(8))) short bf16x8;
typedef __attribute__((ext_vector_type(4))) float f32x4;
typedef unsigned int uint;

// ---------------------------------------------------------------------------
// Helpers
// ---------------------------------------------------------------------------
__device__ inline void seg_bounds(const int* __restrict__ entity_ids, int e,
                                  int& start, int& end) {
    int lo = 0, hi = NMEN;
    while (lo < hi) { int mid = (lo + hi) >> 1; if (entity_ids[mid] < e) lo = mid + 1; else hi = mid; }
    start = lo;
    hi = NMEN;
    while (lo < hi) { int mid = (lo + hi) >> 1; if (entity_ids[mid] <= e) lo = mid + 1; else hi = mid; }
    end = lo;
}

__device__ __forceinline__ void load_lds16(const void* g, void* l) {
    __builtin_amdgcn_global_load_lds(
        (const __attribute__((address_space(1))) uint32_t*)g,
        (__attribute__((address_space(3))) uint32_t*)l,
        16, 0, 0);
}

__device__ __forceinline__ float bflo(uint u) { return __uint_as_float(u << 16); }
__device__ __forceinline__ float bfhi(uint u) { return __uint_as_float(u & 0xffff0000u); }
__device__ __forceinline__ uint pk2(float a, float b) {
    __hip_bfloat16 ha = __float2bfloat16(a), hb = __float2bfloat16(b);
    unsigned short ua = *(unsigned short*)&ha, ub = *(unsigned short*)&hb;
    return (uint)ua | ((uint)ub << 16);
}

// ---------------------------------------------------------------------------
// Transpose fp32 -> bf16: out[c][r] = bf16(in[r][c])
// ---------------------------------------------------------------------------
__global__ void transpose_bf16(const float* __restrict__ in, __hip_bfloat16* __restrict__ out,
                               int R, int C)
{
    __shared__ float t[32][33];
    int r0 = blockIdx.y * 32, c0 = blockIdx.x * 32;
    int j = threadIdx.x & 31, i0 = threadIdx.x >> 5;
    for (int i = i0; i < 32; i += 8)
        t[i][j] = in[(long)(r0 + i) * C + c0 + j];
    __syncthreads();
    for (int i = i0; i < 32; i += 8)
        out[(long)(c0 + i) * R + r0 + j] = __float2bfloat16(t[j][i]);
}

// 4 weight matrices [1024][1024] in one launch (z selects)
__global__ void transpose4_bf16(const float* __restrict__ w0, const float* __restrict__ w1,
                                const float* __restrict__ w2, const float* __restrict__ w3,
                                __hip_bfloat16* __restrict__ o0, __hip_bfloat16* __restrict__ o1,
                                __hip_bfloat16* __restrict__ o2, __hip_bfloat16* __restrict__ o3)
{
    __shared__ float t[32][33];
    const float* in = (blockIdx.z == 0) ? w0 : (blockIdx.z == 1) ? w1 : (blockIdx.z == 2) ? w2 : w3;
    __hip_bfloat16* out = (blockIdx.z == 0) ? o0 : (blockIdx.z == 1) ? o1 : (blockIdx.z == 2) ? o2 : o3;
    int r0 = blockIdx.y * 32, c0 = blockIdx.x * 32;
    int j = threadIdx.x & 31, i0 = threadIdx.x >> 5;
    for (int i = i0; i < 32; i += 8)
        t[i][j] = in[(long)(r0 + i) * 1024 + c0 + j];
    __syncthreads();
    for (int i = i0; i < 32; i += 8)
        out[(long)(c0 + i) * 1024 + r0 + j] = __float2bfloat16(t[j][i]);
}

// ---------------------------------------------------------------------------
// 1) Entity embedding: segment logsumexp -> bf16 [E][H]
// ---------------------------------------------------------------------------
__global__ void ent_emb_kernel(const float4* __restrict__ seq4,
                               const int* __restrict__ mention_idx,
                               const int* __restrict__ entity_ids,
                               __hip_bfloat16* __restrict__ ent_emb)
{
    __shared__ int sb[2];
    int e = blockIdx.x;
    if (threadIdx.x == 0) { int s, t; seg_bounds(entity_ids, e, s, t); sb[0] = s; sb[1] = t; }
    __syncthreads();
    int start = sb[0], end = sb[1];
    int col4 = threadIdx.x;
    uint2 o;
    if (end <= start) {
        o.x = 0; o.y = 0;
        ((uint2*)ent_emb)[(long)e * 256 + col4] = o;
        return;
    }
    float mx = -INFINITY, my = -INFINITY, mz = -INFINITY, mw = -INFINITY;
    for (int i = start; i < end; ++i) {
        float4 v = seq4[(long)mention_idx[i] * 256 + col4];
        mx = fmaxf(mx, v.x); my = fmaxf(my, v.y); mz = fmaxf(mz, v.z); mw = fmaxf(mw, v.w);
    }
    float sx = 0.f, sy = 0.f, sz = 0.f, sw = 0.f;
    for (int i = start; i < end; ++i) {
        float4 v = seq4[(long)mention_idx[i] * 256 + col4];
        sx += expf(v.x - mx); sy += expf(v.y - my); sz += expf(v.z - mz); sw += expf(v.w - mw);
    }
    o.x = pk2(mx + logf(sx), my + logf(sy));
    o.y = pk2(mz + logf(sz), mw + logf(sw));
    ((uint2*)ent_emb)[(long)e * 256 + col4] = o;
}

// ---------------------------------------------------------------------------
// 2) Entity attention: segment mean -> bf16 [E][HEADS][S]
// ---------------------------------------------------------------------------
__global__ void ent_att_kernel(const float4* __restrict__ att4,
                               const int* __restrict__ mention_idx,
                               const int* __restrict__ entity_ids,
                               uint2* __restrict__ out)              // [E*HEADS][S/4] packed bf16
{
    __shared__ int sb[2];
    int e = blockIdx.x, h = blockIdx.y;
    if (threadIdx.x == 0) { int s, t; seg_bounds(entity_ids, e, s, t); sb[0] = s; sb[1] = t; }
    __syncthreads();
    int start = sb[0], end = sb[1];
    float inv = 1.f / fmaxf((float)(end - start), 1.f);
    for (int s4 = threadIdx.x; s4 < S_LEN / 4; s4 += 256) {
        float ax = 0.f, ay = 0.f, az = 0.f, aw = 0.f;
        for (int i = start; i < end; ++i) {
            float4 v = att4[((long)h * S_LEN + mention_idx[i]) * (S_LEN / 4) + s4];
            ax += v.x; ay += v.y; az += v.z; aw += v.w;
        }
        uint2 o; o.x = pk2(ax * inv, ay * inv); o.y = pk2(az * inv, aw * inv);
        out[((long)e * NHEADS + h) * (S_LEN / 4) + s4] = o;
    }
}

// ---------------------------------------------------------------------------
// 3) Pair attention: bf16 in, bf16 normalized out. All-register accumulation.
//    grid NP, 256 threads (each thread owns 8 consecutive s)
// ---------------------------------------------------------------------------
__global__ void pair_att_kernel(const uint4* __restrict__ ea,        // [E][HEADS][S/8] bf16-packed
                                const int* __restrict__ pair_h,
                                const int* __restrict__ pair_t,
                                uint4* __restrict__ patt)            // [P][S/8] bf16-packed
{
    __shared__ float wsum[4];
    int p = blockIdx.x;
    long bh = (long)pair_h[p] * NHEADS * (S_LEN / 8);
    long bt = (long)pair_t[p] * NHEADS * (S_LEN / 8);
    int s8 = threadIdx.x;  // 0..255 covers S/8 exactly
    float a0 = 0, a1 = 0, a2 = 0, a3 = 0, a4 = 0, a5 = 0, a6 = 0, a7 = 0;
#pragma unroll
    for (int h = 0; h < NHEADS; ++h) {
        uint4 xa = ea[bh + h * (S_LEN / 8) + s8];
        uint4 xb = ea[bt + h * (S_LEN / 8) + s8];
        a0 += bflo(xa.x) * bflo(xb.x); a1 += bfhi(xa.x) * bfhi(xb.x);
        a2 += bflo(xa.y) * bflo(xb.y); a3 += bfhi(xa.y) * bfhi(xb.y);
        a4 += bflo(xa.z) * bflo(xb.z); a5 += bfhi(xa.z) * bfhi(xb.z);
        a6 += bflo(xa.w) * bflo(xb.w); a7 += bfhi(xa.w) * bfhi(xb.w);
    }
    float psum = a0 + a1 + a2 + a3 + a4 + a5 + a6 + a7;
#pragma unroll
    for (int off = 32; off > 0; off >>= 1)
        psum += __shfl_down(psum, off, 64);
    int lane = threadIdx.x & 63, wid = threadIdx.x >> 6;
    if (lane == 0) wsum[wid] = psum;
    __syncthreads();
    float inv = 1.f / (wsum[0] + wsum[1] + wsum[2] + wsum[3] + 1e-6f);
    uint4 o;
    o.x = pk2(a0 * inv, a1 * inv); o.y = pk2(a2 * inv, a3 * inv);
    o.z = pk2(a4 * inv, a5 * inv); o.w = pk2(a6 * inv, a7 * inv);
    patt[(long)p * (S_LEN / 8) + s8] = o;
}

// ---------------------------------------------------------------------------
// 4) bf16 MFMA GEMM, 128x128 tile, BK=32, 4 waves (2x2), split-K via blockIdx.z.
//    MODE 0: write fp32 partial slice at Cout + z*M*N
//    MODE 2: fused bilinear: atomicAdd(out+row, sum_col acc*zo[row][col])
// ---------------------------------------------------------------------------
template <int MODE>
__launch_bounds__(256)
__global__ void gemm_bt(const __hip_bfloat16* __restrict__ A,
                        const __hip_bfloat16* __restrict__ Bt,
                        float* __restrict__ Cout,
                        const float* __restrict__ zo,
                        float* __restrict__ out,
                        int M, int N, int Kstride, int kLen)
{
    __shared__ short As[4][128][8];
    __shared__ short Bs[4][128][8];

    int tid = threadIdx.x;
    int lane = tid & 63, wid = tid >> 6;
    int wr = wid >> 1, wc = wid & 1;
    int bm = blockIdx.y * 128, bn = blockIdx.x * 128;
    int kBeg = blockIdx.z * kLen;

    const __hip_bfloat16* gsrc[4];
    void* ldst[4];
#pragma unroll
    for (int i = 0; i < 4; ++i) {
        int c = wid * 4 + i;
        int isA = (c < 8) ? 1 : 0;
        int cc = isA ? c : c - 8;
        int kg = cc >> 1, rh = cc & 1;
        gsrc[i] = (isA ? A + (long)(bm + rh * 64 + lane) * Kstride
                       : Bt + (long)(bn + rh * 64 + lane) * Kstride) + kBeg + kg * 8;
        ldst[i] = isA ? (void*)&As[kg][rh * 64][0] : (void*)&Bs[kg][rh * 64][0];
    }

    f32x4 acc[4][4] = {};
    int kg = lane >> 4, lr = lane & 15;

    for (int k0 = 0; k0 < kLen; k0 += 32) {
#pragma unroll
        for (int i = 0; i < 4; ++i)
            load_lds16(gsrc[i] + k0, ldst[i]);
        __syncthreads();

        bf16x8 af[4], bfr[4];
#pragma unroll
        for (int f = 0; f < 4; ++f) {
            af[f]  = *(const bf16x8*)&As[kg][wr * 64 + f * 16 + lr][0];
            bfr[f] = *(const bf16x8*)&Bs[kg][wc * 64 + f * 16 + lr][0];
        }
#pragma unroll
        for (int fm = 0; fm < 4; ++fm)
#pragma unroll
            for (int fn = 0; fn < 4; ++fn)
                acc[fm][fn] = __builtin_amdgcn_mfma_f32_16x16x32_bf16(af[fm], bfr[fn], acc[fm][fn], 0, 0, 0);
        __syncthreads();
    }

    int q4 = (lane >> 4) * 4;
    if (MODE == 0) {
#pragma unroll
        for (int fm = 0; fm < 4; ++fm)
#pragma unroll
            for (int fn = 0; fn < 4; ++fn) {
                int row = bm + wr * 64 + fm * 16 + q4;
                int col = bn + wc * 64 + fn * 16 + lr;
#pragma unroll
                for (int r = 0; r < 4; ++r)
                    Cout[((long)blockIdx.z * M + row + r) * N + col] = acc[fm][fn][r];
            }
    } else {
        // fused bilinear: per-row dot with zo, shfl-reduce over 16-lane col group
#pragma unroll
        for (int fm = 0; fm < 4; ++fm) {
#pragma unroll
            for (int r = 0; r < 4; ++r) {
                int row = bm + wr * 64 + fm * 16 + q4 + r;
                float v = 0.f;
#pragma unroll
                for (int fn = 0; fn < 4; ++fn) {
                    int col = bn + wc * 64 + fn * 16 + lr;
                    v += acc[fm][fn][r] * zo[(long)row * N + col];
                }
                v += __shfl_xor(v, 1, 64);
                v += __shfl_xor(v, 2, 64);
                v += __shfl_xor(v, 4, 64);
                v += __shfl_xor(v, 8, 64);
                if (lr == 0) atomicAdd(out + row, v);
            }
        }
    }
}

// ---------------------------------------------------------------------------
// 5) reduce 2 split-K fp32 slices -> bf16
// ---------------------------------------------------------------------------
__global__ void reduce2_bf16(const float* __restrict__ part, __hip_bfloat16* __restrict__ o, long n)
{
    long i = (long)blockIdx.x * 256 + threadIdx.x;
    o[i] = __float2bfloat16(part[i] + part[n + i]);
}

// ---------------------------------------------------------------------------
// 6) zs/zo: folds ctxp 2-slice sum + ehet 4-slice sum
// ---------------------------------------------------------------------------
__global__ void zs_zo_kernel(const float* __restrict__ ctxpP,  // [2][P][PH]
                             const float* __restrict__ ehetP,  // [4][E][2PH]
                             const float* __restrict__ b_head,
                             const float* __restrict__ b_tail,
                             const int* __restrict__ pair_h,
                             const int* __restrict__ pair_t,
                             __hip_bfloat16* __restrict__ zs, float* __restrict__ zo)
{
    long idx = (long)blockIdx.x * 256 + threadIdx.x;
    int p = (int)(idx >> 10);
    int j = (int)(idx & (PHID - 1));
    float c = ctxpP[idx] + ctxpP[(long)NP * PHID + idx];
    long hb = (long)pair_h[p] * 2048 + j;
    long tb = (long)pair_t[p] * 2048 + 1024 + j;
    float hs = b_head[j], ts = b_tail[j];
#pragma unroll
    for (int s = 0; s < 4; ++s) {
        hs += ehetP[(long)s * NE * 2048 + hb];
        ts += ehetP[(long)s * NE * 2048 + tb];
    }
    zs[idx] = __float2bfloat16(tanhf(hs + c));
    zo[idx] = tanhf(ts + c);
}

// ---------------------------------------------------------------------------
// 7) bias init for fused-atomic output
// ---------------------------------------------------------------------------
__global__ void bias_init(float* __restrict__ out, const float* __restrict__ b_bil)
{
    out[blockIdx.x * 256 + threadIdx.x] = b_bil[0];
}

// ---------------------------------------------------------------------------
// Launch
// ---------------------------------------------------------------------------
extern "C" void kernel_launch(void* const* d_in, const int* in_sizes, int n_in,
                              void* d_out, int out_size, void* d_ws, size_t ws_size,
                              hipStream_t stream)
{
    const float* seq        = (const float*)d_in[0];
    const float* attention  = (const float*)d_in[1];
    const int*   mention_idx= (const int*)  d_in[2];
    const int*   entity_ids = (const int*)  d_in[3];
    const int*   pair_h     = (const int*)  d_in[4];
    const int*   pair_t     = (const int*)  d_in[5];
    const float* W_head     = (const float*)d_in[6];
    const float* b_head     = (const float*)d_in[7];
    const float* W_tail     = (const float*)d_in[8];
    const float* b_tail     = (const float*)d_in[9];
    const float* W_ctx      = (const float*)d_in[10];
    const float* W_bil      = (const float*)d_in[11];
    const float* b_bil      = (const float*)d_in[12];
    float* out = (float*)d_out;

    // ---- workspace (byte offsets, all MB-aligned) ----
    char* w = (char*)d_ws;
    __hip_bfloat16* seqT  = (__hip_bfloat16*)(w + 0);          // [H][S]    4 MB
    __hip_bfloat16* WctxT = (__hip_bfloat16*)(w + (4l << 20)); // [PH][H]   2 MB
    __hip_bfloat16* WhtT  = (__hip_bfloat16*)(w + (6l << 20)); // [2PH][H]  4 MB
    __hip_bfloat16* WbilT = (__hip_bfloat16*)(w + (10l << 20));// [PH][PH]  2 MB
    __hip_bfloat16* embB  = (__hip_bfloat16*)(w + (12l << 20));// [E][H]    0.5 MB
    __hip_bfloat16* eaB   = (__hip_bfloat16*)(w + (13l << 20));// [E][16][S] bf16 16 MB
    __hip_bfloat16* pattB = (__hip_bfloat16*)(w + (29l << 20));// [P][S]    8 MB
    __hip_bfloat16* ctxB  = (__hip_bfloat16*)(w + (37l << 20));// [P][H]    4 MB
    __hip_bfloat16* zsB   = (__hip_bfloat16*)(w + (41l << 20));// [P][PH]   4 MB
    float* zo    = (float*)(w + (45l << 20));                  // [P][PH]   8 MB
    float* cpart = (float*)(w + (53l << 20));                  // [2][P][H] 16 MB
    float* ctxpP = (float*)(w + (69l << 20));                  // [2][P][PH]16 MB
    float* ehetP = (float*)(w + (85l << 20));                  // [4][E][2PH]8 MB

    // ---- 0) out = b_bil; transposes ----
    bias_init<<<NP / 256, 256, 0, stream>>>(out, b_bil);
    transpose_bf16<<<dim3(HID / 32, S_LEN / 32), 256, 0, stream>>>(seq, seqT, S_LEN, HID);
    transpose4_bf16<<<dim3(32, 32, 4), 256, 0, stream>>>(W_ctx, W_head, W_tail, W_bil,
                                                         WctxT, WhtT, WhtT + (long)PHID * HID, WbilT);

    // ---- 1) entity embeddings (bf16) ----
    ent_emb_kernel<<<NE, 256, 0, stream>>>((const float4*)seq, mention_idx, entity_ids, embB);

    // ---- 2) entity attention (bf16) ----
    ent_att_kernel<<<dim3(NE, NHEADS), 256, 0, stream>>>((const float4*)attention, mention_idx, entity_ids,
                                                         (uint2*)eaB);

    // ---- 3) pair attention (bf16 normalized) ----
    pair_att_kernel<<<NP, 256, 0, stream>>>((const uint4*)eaB, pair_h, pair_t, (uint4*)pattB);

    // ---- 4) contexts = pair_att @ seq, splitK=2 -> fp32 partials -> bf16 ----
    gemm_bt<0><<<dim3(HID / 128, NP / 128, 2), 256, 0, stream>>>(pattB, seqT, cpart, nullptr, nullptr,
                                                                 NP, HID, S_LEN, S_LEN / 2);
    reduce2_bf16<<<(int)(((long)NP * HID) / 256), 256, 0, stream>>>(cpart, ctxB, (long)NP * HID);

    // ---- 5) ctxp partials = contexts @ W_ctx, splitK=2 (summed in zs_zo) ----
    gemm_bt<0><<<dim3(PHID / 128, NP / 128, 2), 256, 0, stream>>>(ctxB, WctxT, ctxpP, nullptr, nullptr,
                                                                  NP, PHID, HID, HID / 2);

    // ---- 6) ehet partials = ent_emb @ [W_head|W_tail], splitK=4 (summed in zs_zo) ----
    gemm_bt<0><<<dim3(2 * PHID / 128, NE / 128, 4), 256, 0, stream>>>(embB, WhtT, ehetP, nullptr, nullptr,
                                                                      NE, 2 * PHID, HID, HID / 4);

    // ---- 7) zs (bf16), zo (f32) ----
    zs_zo_kernel<<<(int)(((long)NP * PHID) / 256), 256, 0, stream>>>(ctxpP, ehetP, b_head, b_tail,
                                                                    pair_h, pair_t, zsB, zo);

    // ---- 8) fused bilinear: out[p] += sum_j (zs@W_bil)[p,j] * zo[p,j], splitK=2 ----
    gemm_bt<2><<<dim3(PHID / 128, NP / 128, 2), 256, 0, stream>>>(zsB, WbilT, nullptr, zo, out,
                                                                  NP, PHID, HID, HID / 2);
}